// Round 1
// baseline (922.536 us; speedup 1.0000x reference)
//
#include <hip/hip_runtime.h>
#include <stdint.h>
#include <math.h>

#define NTOK 16384
#define HID  2048
#define NGRP 16          // HID/128
#define EPSF 1e-5f

typedef __bf16 bf16;
typedef __bf16 bf16x8 __attribute__((ext_vector_type(8)));
typedef float  f32x4  __attribute__((ext_vector_type(4)));

// ---------------- helpers ----------------

__device__ __forceinline__ void async_load16(const void* g, void* l) {
  __builtin_amdgcn_global_load_lds((const __attribute__((address_space(1))) void*)g,
                                   (__attribute__((address_space(3))) void*)l, 16, 0, 0);
}

// bit-exact fp8 e4m3fn round-to-nearest-even; input must be pre-clipped to [-448,448]
__device__ __forceinline__ float fp8_e4m3_rne(float v) {
  float a = fabsf(v);
  float s = (v < 0.f) ? -1.f : 1.f;
  if (a < 0.015625f) {                 // below 2^-6: fp8 subnormal, quantum 2^-9
    float r = rintf(a * 512.0f);       // v_rndne = RNE
    return s * r * 0.001953125f;
  }
  uint32_t u = __float_as_uint(a);
  u = (u + 0x7FFFFu + ((u >> 20) & 1u)) & 0xFFF00000u;  // RNE to 3 mantissa bits
  return s * __uint_as_float(u);
}

__device__ __forceinline__ float block_sum256(float v) {
  __shared__ float sh[4];
  #pragma unroll
  for (int o = 32; o > 0; o >>= 1) v += __shfl_xor(v, o, 64);
  if ((threadIdx.x & 63) == 0) sh[threadIdx.x >> 6] = v;
  __syncthreads();
  return sh[0] + sh[1] + sh[2] + sh[3];
}

// ue8m0 scale: exp2(ceil(log2(max(amax,1e-10)/448))), emulating numpy fp32 semantics
__device__ __forceinline__ float ue8m0_scale(float amax) {
  float v = fmaxf(amax, 1e-10f) / 448.0f;
  float l = (float)log2((double)v);    // correctly-rounded; exact at powers of 2
  return exp2f(ceilf(l));
}

// ---------------- kernels ----------------

// w[z][k][n] f32 -> Wt[z][n][k] bf16   (B^T layout for the GEMM)
__global__ __launch_bounds__(256) void k_transpose_cast(const float* __restrict__ W,
                                                        bf16* __restrict__ Wt) {
  __shared__ float tile[32][33];
  const size_t mat = (size_t)HID * HID;
  const float* Wz = W + mat * blockIdx.z;
  bf16* Wtz = Wt + mat * blockIdx.z;
  int bx = blockIdx.x * 32;   // n base
  int by = blockIdx.y * 32;   // k base
  int lx = threadIdx.x & 31;
  int ly = threadIdx.x >> 5;  // 0..7
  #pragma unroll
  for (int r = 0; r < 4; r++)
    tile[ly + r * 8][lx] = Wz[(size_t)(by + ly + r * 8) * HID + bx + lx];
  __syncthreads();
  #pragma unroll
  for (int r = 0; r < 4; r++)
    Wtz[(size_t)(bx + ly + r * 8) * HID + by + lx] = (bf16)tile[lx][ly + r * 8];
}

// y = rmsnorm(relu(x)) * nw  -> bf16.  one block per row.
__global__ __launch_bounds__(256) void k_pre(const float* __restrict__ x,
                                             const float* __restrict__ nw,
                                             bf16* __restrict__ Y) {
  size_t base = (size_t)blockIdx.x * HID + threadIdx.x * 8;
  float4 v0 = *(const float4*)(x + base);
  float4 v1 = *(const float4*)(x + base + 4);
  float z[8] = {v0.x, v0.y, v0.z, v0.w, v1.x, v1.y, v1.z, v1.w};
  float ss = 0.f;
  #pragma unroll
  for (int i = 0; i < 8; i++) { z[i] = fmaxf(z[i], 0.f); ss += z[i] * z[i]; }
  float tot = block_sum256(ss);
  float s = rsqrtf(tot * (1.0f / HID) + EPSF);
  int j0 = threadIdx.x * 8;
  float4 w0 = *(const float4*)(nw + j0);
  float4 w1 = *(const float4*)(nw + j0 + 4);
  float wv[8] = {w0.x, w0.y, w0.z, w0.w, w1.x, w1.y, w1.z, w1.w};
  bf16x8 o;
  #pragma unroll
  for (int i = 0; i < 8; i++) o[i] = (bf16)(z[i] * s * wv[i]);
  *(bf16x8*)(Y + base) = o;
}

// resid = (mode0 ? relu(x) : residIn) + Cin ; y = rmsnorm(resid)*nw ;
// per-128-group ue8m0 quant -> Aout(bf16 of fp8 values), scaleOut; residOut(bf16)
__global__ __launch_bounds__(256) void k_fuse_quant(const float* __restrict__ xResid,
                                                    const bf16* __restrict__ residIn,
                                                    const bf16* __restrict__ Cin,
                                                    const float* __restrict__ nw,
                                                    bf16* __restrict__ residOut,
                                                    bf16* __restrict__ Aout,
                                                    float* __restrict__ scaleOut,
                                                    int mode) {
  int row = blockIdx.x;
  int j0 = threadIdx.x * 8;
  size_t base = (size_t)row * HID + j0;
  bf16x8 c = *(const bf16x8*)(Cin + base);
  float r[8];
  if (mode == 0) {
    float4 v0 = *(const float4*)(xResid + base);
    float4 v1 = *(const float4*)(xResid + base + 4);
    float xv[8] = {v0.x, v0.y, v0.z, v0.w, v1.x, v1.y, v1.z, v1.w};
    #pragma unroll
    for (int i = 0; i < 8; i++) r[i] = fmaxf(xv[i], 0.f) + (float)c[i];
  } else {
    bf16x8 rv = *(const bf16x8*)(residIn + base);
    #pragma unroll
    for (int i = 0; i < 8; i++) r[i] = (float)rv[i] + (float)c[i];
  }
  float ss = 0.f;
  #pragma unroll
  for (int i = 0; i < 8; i++) ss += r[i] * r[i];
  float tot = block_sum256(ss);
  float s = rsqrtf(tot * (1.0f / HID) + EPSF);

  bf16x8 ro;
  #pragma unroll
  for (int i = 0; i < 8; i++) ro[i] = (bf16)r[i];
  *(bf16x8*)(residOut + base) = ro;

  float4 w0 = *(const float4*)(nw + j0);
  float4 w1 = *(const float4*)(nw + j0 + 4);
  float wv[8] = {w0.x, w0.y, w0.z, w0.w, w1.x, w1.y, w1.z, w1.w};
  float y[8], amax = 0.f;
  #pragma unroll
  for (int i = 0; i < 8; i++) { y[i] = r[i] * s * wv[i]; amax = fmaxf(amax, fabsf(y[i])); }
  // group = 128 elems = 16 consecutive lanes
  amax = fmaxf(amax, __shfl_xor(amax, 1, 64));
  amax = fmaxf(amax, __shfl_xor(amax, 2, 64));
  amax = fmaxf(amax, __shfl_xor(amax, 4, 64));
  amax = fmaxf(amax, __shfl_xor(amax, 8, 64));
  float scale = ue8m0_scale(amax);
  float inv = 1.0f / scale;          // exact: scale is a power of 2
  bf16x8 q;
  #pragma unroll
  for (int i = 0; i < 8; i++) {
    float t = fminf(fmaxf(y[i] * inv, -448.f), 448.f);
    q[i] = (bf16)fp8_e4m3_rne(t);    // fp8 values are exact in bf16
  }
  *(bf16x8*)(Aout + base) = q;
  if ((threadIdx.x & 15) == 0) scaleOut[(size_t)row * NGRP + (j0 >> 7)] = scale;
}

// y4 = rmsnorm(residIn + Cin) * nw -> f32 out
__global__ __launch_bounds__(256) void k_final(const bf16* __restrict__ residIn,
                                               const bf16* __restrict__ Cin,
                                               const float* __restrict__ nw,
                                               float* __restrict__ out) {
  size_t base = (size_t)blockIdx.x * HID + threadIdx.x * 8;
  bf16x8 c = *(const bf16x8*)(Cin + base);
  bf16x8 rv = *(const bf16x8*)(residIn + base);
  float r[8]; float ss = 0.f;
  #pragma unroll
  for (int i = 0; i < 8; i++) { r[i] = (float)rv[i] + (float)c[i]; ss += r[i] * r[i]; }
  float tot = block_sum256(ss);
  float s = rsqrtf(tot * (1.0f / HID) + EPSF);
  int j0 = threadIdx.x * 8;
  float4 w0 = *(const float4*)(nw + j0);
  float4 w1 = *(const float4*)(nw + j0 + 4);
  float wv[8] = {w0.x, w0.y, w0.z, w0.w, w1.x, w1.y, w1.z, w1.w};
  float4 o0, o1;
  o0.x = r[0]*s*wv[0]; o0.y = r[1]*s*wv[1]; o0.z = r[2]*s*wv[2]; o0.w = r[3]*s*wv[3];
  o1.x = r[4]*s*wv[4]; o1.y = r[5]*s*wv[5]; o1.z = r[6]*s*wv[6]; o1.w = r[7]*s*wv[7];
  *(float4*)(out + base) = o0;
  *(float4*)(out + base + 4) = o1;
}

// C[M][N] = A[M][K] * B^T[N][K], bf16 in, fp32 acc, bf16 out.
// m97 structure: 128x128 tile, BK=32, global_load_lds width 16, 16x16x32 MFMA.
__global__ __launch_bounds__(256) void k_gemm(const bf16* __restrict__ A,
                                              const bf16* __restrict__ B,
                                              bf16* __restrict__ C,
                                              int M, int N, int K) {
  __shared__ __align__(16) bf16 As[128 * 32];
  __shared__ __align__(16) bf16 Bs[128 * 32];
  int bm = blockIdx.y, bn = blockIdx.x;
  int tid = threadIdx.x;
  int wave = tid >> 6, lane = tid & 63;
  int q = lane >> 4, rr = lane & 15;

  // staging: thread t loads 16B; row = t/4, k-elem = (t%4)*8; 2 passes of 64 rows
  int srow = tid >> 2;
  int scol = (tid & 3) * 8;
  const bf16* Ap = A + ((size_t)(bm * 128 + srow) * K + scol);
  const bf16* Bp = B + ((size_t)(bn * 128 + srow) * K + scol);
  char* AsB = (char*)As;
  char* BsB = (char*)Bs;
  uint32_t ldsOff = (uint32_t)wave * 1024;

  f32x4 acc[4][4];
  #pragma unroll
  for (int mi = 0; mi < 4; mi++)
    #pragma unroll
    for (int ni = 0; ni < 4; ni++)
      #pragma unroll
      for (int e = 0; e < 4; e++) acc[mi][ni][e] = 0.f;

  int m_off = (wave >> 1) * 64;
  int n_off = (wave & 1) * 64;

  for (int k0 = 0; k0 < K; k0 += 32) {
    __syncthreads();  // all waves done reading LDS from previous iter
    async_load16(Ap + k0,                 AsB + ldsOff);
    async_load16(Ap + (size_t)64 * K + k0, AsB + 4096 + ldsOff);
    async_load16(Bp + k0,                 BsB + ldsOff);
    async_load16(Bp + (size_t)64 * K + k0, BsB + 4096 + ldsOff);
    __syncthreads();  // vmcnt(0) drain: staged tile visible

    bf16x8 af[4], bfr[4];
    #pragma unroll
    for (int mi = 0; mi < 4; mi++)
      af[mi] = *(const bf16x8*)(As + (m_off + mi * 16 + rr) * 32 + q * 8);
    #pragma unroll
    for (int ni = 0; ni < 4; ni++)
      bfr[ni] = *(const bf16x8*)(Bs + (n_off + ni * 16 + rr) * 32 + q * 8);
    #pragma unroll
    for (int mi = 0; mi < 4; mi++)
      #pragma unroll
      for (int ni = 0; ni < 4; ni++)
        acc[mi][ni] = __builtin_amdgcn_mfma_f32_16x16x32_bf16(af[mi], bfr[ni], acc[mi][ni], 0, 0, 0);
  }

  // epilogue: C/D layout col=lane&15, row=(lane>>4)*4+reg
  #pragma unroll
  for (int mi = 0; mi < 4; mi++)
    #pragma unroll
    for (int ni = 0; ni < 4; ni++)
      #pragma unroll
      for (int t = 0; t < 4; t++) {
        int rowi = bm * 128 + m_off + mi * 16 + q * 4 + t;
        int coli = bn * 128 + n_off + ni * 16 + rr;
        C[(size_t)rowi * N + coli] = (bf16)acc[mi][ni][t];
      }
}

// ---------------- launch ----------------

extern "C" void kernel_launch(void* const* d_in, const int* in_sizes, int n_in,
                              void* d_out, int out_size, void* d_ws, size_t ws_size,
                              hipStream_t stream) {
  const float* x      = (const float*)d_in[0];
  const float* norm_w = (const float*)d_in[1];
  const float* w      = (const float*)d_in[2];

  float* out   = (float*)d_out;
  float* y4o   = out;
  float* s2o   = out + (size_t)NTOK * HID;           // y2_s [16384,16]
  float* s3o   = s2o + (size_t)NTOK * NGRP;          // y3_s [16384,16]

  char* ws = (char*)d_ws;
  const size_t WT_B = (size_t)3 * HID * HID * 2;     // 25,165,824
  const size_t AB_B = (size_t)NTOK * HID * 2;        // 67,108,864
  bf16* Wt   = (bf16*)ws;
  bf16* Abuf = (bf16*)(ws + WT_B);
  bf16* Cbuf = (bf16*)(ws + WT_B + AB_B);
  bf16* Rbuf = (bf16*)(ws + WT_B + 2 * AB_B);
  const size_t MATE = (size_t)HID * HID;

  dim3 gT(64, 64, 3);
  dim3 gG(HID / 128, NTOK / 128);

  k_transpose_cast<<<gT, 256, 0, stream>>>(w, Wt);
  k_pre<<<NTOK, 256, 0, stream>>>(x, norm_w, Abuf);
  k_gemm<<<gG, 256, 0, stream>>>(Abuf, Wt, Cbuf, NTOK, HID, HID);
  k_fuse_quant<<<NTOK, 256, 0, stream>>>(x, nullptr, Cbuf, norm_w + HID, Rbuf, Abuf, s2o, 0);
  k_gemm<<<gG, 256, 0, stream>>>(Abuf, Wt + MATE, Cbuf, NTOK, HID, HID);
  k_fuse_quant<<<NTOK, 256, 0, stream>>>(nullptr, Rbuf, Cbuf, norm_w + 2 * HID, Rbuf, Abuf, s3o, 1);
  k_gemm<<<gG, 256, 0, stream>>>(Abuf, Wt + 2 * MATE, Cbuf, NTOK, HID, HID);
  k_final<<<NTOK, 256, 0, stream>>>(Rbuf, Cbuf, norm_w + 3 * HID, y4o);
}

// Round 2
// 810.551 us; speedup vs baseline: 1.1382x; 1.1382x over previous
//
#include <hip/hip_runtime.h>
#include <stdint.h>
#include <math.h>

#define NTOK 16384
#define HID  2048
#define NGRP 16          // HID/128
#define EPSF 1e-5f

typedef __bf16 bf16;
typedef __bf16 bf16x8 __attribute__((ext_vector_type(8)));
typedef float  f32x4  __attribute__((ext_vector_type(4)));

// ---------------- helpers ----------------

__device__ __forceinline__ void async_load16(const void* g, void* l) {
  __builtin_amdgcn_global_load_lds((const __attribute__((address_space(1))) void*)g,
                                   (__attribute__((address_space(3))) void*)l, 16, 0, 0);
}

// bit-exact fp8 e4m3fn round-to-nearest-even; input must be pre-clipped to [-448,448]
__device__ __forceinline__ float fp8_e4m3_rne(float v) {
  float a = fabsf(v);
  float s = (v < 0.f) ? -1.f : 1.f;
  if (a < 0.015625f) {                 // below 2^-6: fp8 subnormal, quantum 2^-9
    float r = rintf(a * 512.0f);       // v_rndne = RNE
    return s * r * 0.001953125f;
  }
  uint32_t u = __float_as_uint(a);
  u = (u + 0x7FFFFu + ((u >> 20) & 1u)) & 0xFFF00000u;  // RNE to 3 mantissa bits
  return s * __uint_as_float(u);
}

__device__ __forceinline__ float wave_sum(float v) {
  #pragma unroll
  for (int o = 32; o > 0; o >>= 1) v += __shfl_xor(v, o, 64);
  return v;
}

// ue8m0 scale: exp2(ceil(log2(max(amax,1e-10)/448))), emulating numpy fp32 semantics
__device__ __forceinline__ float ue8m0_scale(float amax) {
  float v = fmaxf(amax, 1e-10f) / 448.0f;
  float l = (float)log2((double)v);    // correctly-rounded; exact at powers of 2
  return exp2f(ceilf(l));
}

// ---------------- kernels ----------------

// w[z][k][n] f32 -> Wt[z][n][k] bf16   (B^T layout for the GEMM)
__global__ __launch_bounds__(256) void k_transpose_cast(const float* __restrict__ W,
                                                        bf16* __restrict__ Wt) {
  __shared__ float tile[32][33];
  const size_t mat = (size_t)HID * HID;
  const float* Wz = W + mat * blockIdx.z;
  bf16* Wtz = Wt + mat * blockIdx.z;
  int bx = blockIdx.x * 32;   // n base
  int by = blockIdx.y * 32;   // k base
  int lx = threadIdx.x & 31;
  int ly = threadIdx.x >> 5;  // 0..7
  #pragma unroll
  for (int r = 0; r < 4; r++)
    tile[ly + r * 8][lx] = Wz[(size_t)(by + ly + r * 8) * HID + bx + lx];
  __syncthreads();
  #pragma unroll
  for (int r = 0; r < 4; r++)
    Wtz[(size_t)(bx + ly + r * 8) * HID + by + lx] = (bf16)tile[lx][ly + r * 8];
}

// y = rmsnorm(relu(x)) * nw -> bf16.  one WAVE per row (no block barriers).
__global__ __launch_bounds__(256) void k_pre(const float* __restrict__ x,
                                             const float* __restrict__ nw,
                                             bf16* __restrict__ Y) {
  int wave = threadIdx.x >> 6, lane = threadIdx.x & 63;
  int row = blockIdx.x * 4 + wave;
  const float* xr = x + (size_t)row * HID;
  bf16* yr = Y + (size_t)row * HID;
  float z[32]; float ss = 0.f;
  #pragma unroll
  for (int j = 0; j < 4; j++) {
    int col = j * 512 + lane * 8;
    float4 v0 = *(const float4*)(xr + col);
    float4 v1 = *(const float4*)(xr + col + 4);
    float* zz = z + j * 8;
    zz[0]=v0.x; zz[1]=v0.y; zz[2]=v0.z; zz[3]=v0.w;
    zz[4]=v1.x; zz[5]=v1.y; zz[6]=v1.z; zz[7]=v1.w;
    #pragma unroll
    for (int i = 0; i < 8; i++) { zz[i] = fmaxf(zz[i], 0.f); ss += zz[i]*zz[i]; }
  }
  float s = rsqrtf(wave_sum(ss) * (1.0f / HID) + EPSF);
  #pragma unroll
  for (int j = 0; j < 4; j++) {
    int col = j * 512 + lane * 8;
    float4 w0 = *(const float4*)(nw + col);
    float4 w1 = *(const float4*)(nw + col + 4);
    float wv[8] = {w0.x, w0.y, w0.z, w0.w, w1.x, w1.y, w1.z, w1.w};
    bf16x8 o;
    #pragma unroll
    for (int i = 0; i < 8; i++) o[i] = (bf16)(z[j*8+i] * s * wv[i]);
    *(bf16x8*)(yr + col) = o;
  }
}

// resid = (mode0 ? relu(x) : residIn) + Cin ; y = rmsnorm(resid)*nw ;
// per-128-group ue8m0 quant -> Aout(bf16 of fp8 values), scaleOut; residOut(bf16)
// one WAVE per row; chunk j covers cols [j*512 + lane*8, +8) -> group j*4 + (lane>>4)
__global__ __launch_bounds__(256) void k_fuse_quant(const float* __restrict__ xResid,
                                                    const bf16* __restrict__ residIn,
                                                    const bf16* __restrict__ Cin,
                                                    const float* __restrict__ nw,
                                                    bf16* __restrict__ residOut,
                                                    bf16* __restrict__ Aout,
                                                    float* __restrict__ scaleOut,
                                                    int mode) {
  int wave = threadIdx.x >> 6, lane = threadIdx.x & 63;
  int row = blockIdx.x * 4 + wave;
  size_t rbase = (size_t)row * HID;
  float r[32]; float ss = 0.f;
  #pragma unroll
  for (int j = 0; j < 4; j++) {
    int col = j * 512 + lane * 8;
    bf16x8 c = *(const bf16x8*)(Cin + rbase + col);
    float* rr = r + j * 8;
    if (mode == 0) {
      float4 v0 = *(const float4*)(xResid + rbase + col);
      float4 v1 = *(const float4*)(xResid + rbase + col + 4);
      float xv[8] = {v0.x, v0.y, v0.z, v0.w, v1.x, v1.y, v1.z, v1.w};
      #pragma unroll
      for (int i = 0; i < 8; i++) rr[i] = fmaxf(xv[i], 0.f) + (float)c[i];
    } else {
      bf16x8 rv = *(const bf16x8*)(residIn + rbase + col);
      #pragma unroll
      for (int i = 0; i < 8; i++) rr[i] = (float)rv[i] + (float)c[i];
    }
    #pragma unroll
    for (int i = 0; i < 8; i++) ss += rr[i] * rr[i];
  }
  float s = rsqrtf(wave_sum(ss) * (1.0f / HID) + EPSF);

  #pragma unroll
  for (int j = 0; j < 4; j++) {
    int col = j * 512 + lane * 8;
    bf16x8 ro;
    #pragma unroll
    for (int i = 0; i < 8; i++) ro[i] = (bf16)r[j*8+i];
    *(bf16x8*)(residOut + rbase + col) = ro;
  }

  #pragma unroll
  for (int j = 0; j < 4; j++) {
    int col = j * 512 + lane * 8;
    float4 w0 = *(const float4*)(nw + col);
    float4 w1 = *(const float4*)(nw + col + 4);
    float wv[8] = {w0.x, w0.y, w0.z, w0.w, w1.x, w1.y, w1.z, w1.w};
    float y[8], amax = 0.f;
    #pragma unroll
    for (int i = 0; i < 8; i++) { y[i] = r[j*8+i] * s * wv[i]; amax = fmaxf(amax, fabsf(y[i])); }
    amax = fmaxf(amax, __shfl_xor(amax, 1, 64));
    amax = fmaxf(amax, __shfl_xor(amax, 2, 64));
    amax = fmaxf(amax, __shfl_xor(amax, 4, 64));
    amax = fmaxf(amax, __shfl_xor(amax, 8, 64));
    float scale = ue8m0_scale(amax);
    float inv = 1.0f / scale;          // exact: scale is a power of 2
    bf16x8 qv;
    #pragma unroll
    for (int i = 0; i < 8; i++) {
      float t = fminf(fmaxf(y[i] * inv, -448.f), 448.f);
      qv[i] = (bf16)fp8_e4m3_rne(t);   // fp8 values are exact in bf16
    }
    *(bf16x8*)(Aout + rbase + col) = qv;
    if ((lane & 15) == 0) scaleOut[(size_t)row * NGRP + j * 4 + (lane >> 4)] = scale;
  }
}

// y4 = rmsnorm(residIn + Cin) * nw -> f32 out.  one WAVE per row.
__global__ __launch_bounds__(256) void k_final(const bf16* __restrict__ residIn,
                                               const bf16* __restrict__ Cin,
                                               const float* __restrict__ nw,
                                               float* __restrict__ out) {
  int wave = threadIdx.x >> 6, lane = threadIdx.x & 63;
  int row = blockIdx.x * 4 + wave;
  size_t rbase = (size_t)row * HID;
  float r[32]; float ss = 0.f;
  #pragma unroll
  for (int j = 0; j < 4; j++) {
    int col = j * 512 + lane * 8;
    bf16x8 c  = *(const bf16x8*)(Cin + rbase + col);
    bf16x8 rv = *(const bf16x8*)(residIn + rbase + col);
    float* rr = r + j * 8;
    #pragma unroll
    for (int i = 0; i < 8; i++) { rr[i] = (float)rv[i] + (float)c[i]; ss += rr[i]*rr[i]; }
  }
  float s = rsqrtf(wave_sum(ss) * (1.0f / HID) + EPSF);
  #pragma unroll
  for (int j = 0; j < 4; j++) {
    int col = j * 512 + lane * 8;
    float4 w0 = *(const float4*)(nw + col);
    float4 w1 = *(const float4*)(nw + col + 4);
    float wv[8] = {w0.x, w0.y, w0.z, w0.w, w1.x, w1.y, w1.z, w1.w};
    float4 o0, o1;
    o0.x = r[j*8+0]*s*wv[0]; o0.y = r[j*8+1]*s*wv[1];
    o0.z = r[j*8+2]*s*wv[2]; o0.w = r[j*8+3]*s*wv[3];
    o1.x = r[j*8+4]*s*wv[4]; o1.y = r[j*8+5]*s*wv[5];
    o1.z = r[j*8+6]*s*wv[6]; o1.w = r[j*8+7]*s*wv[7];
    *(float4*)(out + rbase + col) = o0;
    *(float4*)(out + rbase + col + 4) = o1;
  }
}

// C[M][N] = A[M][K] * B^T[N][K], bf16 in, fp32 acc, bf16 out.
// 128x128 tile, BK=64, global_load_lds width 16, 16x16x32 MFMA.
// LDS layout XOR-swizzled: slot(row, c) holds chunk (c ^ ((row>>1)&7)) of the row
// -> fragment ds_read_b128 is 2-way-per-bank (free); staging permutation applied
//    on the GLOBAL side (global_load_lds scatters base+lane*16, can't scatter LDS).
__global__ __launch_bounds__(256) void k_gemm(const bf16* __restrict__ A,
                                              const bf16* __restrict__ B,
                                              bf16* __restrict__ C,
                                              int M, int N, int K) {
  __shared__ __align__(16) bf16 As[128 * 64];
  __shared__ __align__(16) bf16 Bs[128 * 64];
  int bm = blockIdx.y, bn = blockIdx.x;
  int tid = threadIdx.x;
  int wave = tid >> 6, lane = tid & 63;
  int q = lane >> 4, rr = lane & 15;

  // staging: 4 slots per thread per matrix; slot s = wave*256 + i*64 + lane
  const bf16* Aq[4]; const bf16* Bq[4];
  #pragma unroll
  for (int i = 0; i < 4; i++) {
    int s  = wave * 256 + i * 64 + lane;
    int r  = s >> 3, c = s & 7;
    int gc = c ^ ((r >> 1) & 7);            // swizzled source chunk
    Aq[i] = A + (size_t)(bm * 128 + r) * K + gc * 8;
    Bq[i] = B + (size_t)(bn * 128 + r) * K + gc * 8;
  }
  char* AsB = (char*)As;
  char* BsB = (char*)Bs;

  f32x4 acc[4][4];
  #pragma unroll
  for (int mi = 0; mi < 4; mi++)
    #pragma unroll
    for (int ni = 0; ni < 4; ni++)
      #pragma unroll
      for (int e = 0; e < 4; e++) acc[mi][ni][e] = 0.f;

  int m_off = (wave >> 1) * 64;
  int n_off = (wave & 1) * 64;
  int swz = (rr >> 1) & 7;                  // per-lane read swizzle (row>>1)&7

  // precomputed LDS element offsets for fragment reads (per ms-step below)
  int arow[4], brow[4];
  #pragma unroll
  for (int i = 0; i < 4; i++) {
    arow[i] = (m_off + i * 16 + rr) * 64;
    brow[i] = (n_off + i * 16 + rr) * 64;
  }

  for (int k0 = 0; k0 < K; k0 += 64) {
    __syncthreads();  // all waves done reading LDS from previous iter
    #pragma unroll
    for (int i = 0; i < 4; i++)
      async_load16(Aq[i] + k0, AsB + wave * 4096 + i * 1024);
    #pragma unroll
    for (int i = 0; i < 4; i++)
      async_load16(Bq[i] + k0, BsB + wave * 4096 + i * 1024);
    __syncthreads();  // vmcnt(0) drain: staged tile visible

    #pragma unroll
    for (int ms = 0; ms < 2; ms++) {
      int p = ((ms * 4 + q) ^ swz) * 8;     // swizzled chunk -> element offset
      bf16x8 af[4], bfr[4];
      #pragma unroll
      for (int mi = 0; mi < 4; mi++)
        af[mi] = *(const bf16x8*)(As + arow[mi] + p);
      #pragma unroll
      for (int ni = 0; ni < 4; ni++)
        bfr[ni] = *(const bf16x8*)(Bs + brow[ni] + p);
      #pragma unroll
      for (int mi = 0; mi < 4; mi++)
        #pragma unroll
        for (int ni = 0; ni < 4; ni++)
          acc[mi][ni] = __builtin_amdgcn_mfma_f32_16x16x32_bf16(af[mi], bfr[ni], acc[mi][ni], 0, 0, 0);
    }
  }

  // epilogue: C/D layout col=lane&15, row=(lane>>4)*4+reg
  #pragma unroll
  for (int mi = 0; mi < 4; mi++)
    #pragma unroll
    for (int ni = 0; ni < 4; ni++)
      #pragma unroll
      for (int t = 0; t < 4; t++) {
        int rowi = bm * 128 + m_off + mi * 16 + q * 4 + t;
        int coli = bn * 128 + n_off + ni * 16 + rr;
        C[(size_t)rowi * N + coli] = (bf16)acc[mi][ni][t];
      }
}

// ---------------- launch ----------------

extern "C" void kernel_launch(void* const* d_in, const int* in_sizes, int n_in,
                              void* d_out, int out_size, void* d_ws, size_t ws_size,
                              hipStream_t stream) {
  const float* x      = (const float*)d_in[0];
  const float* norm_w = (const float*)d_in[1];
  const float* w      = (const float*)d_in[2];

  float* out   = (float*)d_out;
  float* y4o   = out;
  float* s2o   = out + (size_t)NTOK * HID;           // y2_s [16384,16]
  float* s3o   = s2o + (size_t)NTOK * NGRP;          // y3_s [16384,16]

  char* ws = (char*)d_ws;
  const size_t WT_B = (size_t)3 * HID * HID * 2;     // 25,165,824
  const size_t AB_B = (size_t)NTOK * HID * 2;        // 67,108,864
  bf16* Wt   = (bf16*)ws;
  bf16* Abuf = (bf16*)(ws + WT_B);
  bf16* Cbuf = (bf16*)(ws + WT_B + AB_B);
  bf16* Rbuf = (bf16*)(ws + WT_B + 2 * AB_B);
  const size_t MATE = (size_t)HID * HID;

  dim3 gT(64, 64, 3);
  dim3 gG(HID / 128, NTOK / 128);
  int gE = NTOK / 4;   // wave-per-row elementwise kernels

  k_transpose_cast<<<gT, 256, 0, stream>>>(w, Wt);
  k_pre<<<gE, 256, 0, stream>>>(x, norm_w, Abuf);
  k_gemm<<<gG, 256, 0, stream>>>(Abuf, Wt, Cbuf, NTOK, HID, HID);
  k_fuse_quant<<<gE, 256, 0, stream>>>(x, nullptr, Cbuf, norm_w + HID, Rbuf, Abuf, s2o, 0);
  k_gemm<<<gG, 256, 0, stream>>>(Abuf, Wt + MATE, Cbuf, NTOK, HID, HID);
  k_fuse_quant<<<gE, 256, 0, stream>>>(nullptr, Rbuf, Cbuf, norm_w + 2 * HID, Rbuf, Abuf, s3o, 1);
  k_gemm<<<gG, 256, 0, stream>>>(Abuf, Wt + 2 * MATE, Cbuf, NTOK, HID, HID);
  k_final<<<gE, 256, 0, stream>>>(Rbuf, Cbuf, norm_w + 3 * HID, y4o);
}

// Round 3
// 799.501 us; speedup vs baseline: 1.1539x; 1.0138x over previous
//
#include <hip/hip_runtime.h>
#include <stdint.h>
#include <math.h>

#define NTOK 16384
#define HID  2048
#define NGRP 16          // HID/128
#define EPSF 1e-5f

typedef __bf16 bf16;
typedef __bf16 bf16x8 __attribute__((ext_vector_type(8)));
typedef float  f32x4  __attribute__((ext_vector_type(4)));

// ---------------- helpers ----------------

__device__ __forceinline__ void async_load16(const void* g, void* l) {
  __builtin_amdgcn_global_load_lds((const __attribute__((address_space(1))) void*)g,
                                   (__attribute__((address_space(3))) void*)l, 16, 0, 0);
}

// bit-exact fp8 e4m3fn round-to-nearest-even; input must be pre-clipped to [-448,448]
__device__ __forceinline__ float fp8_e4m3_rne(float v) {
  float a = fabsf(v);
  float s = (v < 0.f) ? -1.f : 1.f;
  if (a < 0.015625f) {                 // below 2^-6: fp8 subnormal, quantum 2^-9
    float r = rintf(a * 512.0f);       // v_rndne = RNE
    return s * r * 0.001953125f;
  }
  uint32_t u = __float_as_uint(a);
  u = (u + 0x7FFFFu + ((u >> 20) & 1u)) & 0xFFF00000u;  // RNE to 3 mantissa bits
  return s * __uint_as_float(u);
}

__device__ __forceinline__ float block_sum256(float v) {
  __shared__ float sh[4];
  #pragma unroll
  for (int o = 32; o > 0; o >>= 1) v += __shfl_xor(v, o, 64);
  if ((threadIdx.x & 63) == 0) sh[threadIdx.x >> 6] = v;
  __syncthreads();
  return sh[0] + sh[1] + sh[2] + sh[3];
}

// ue8m0 scale: exp2(ceil(log2(max(amax,1e-10)/448))), emulating numpy fp32 semantics
__device__ __forceinline__ float ue8m0_scale(float amax) {
  float v = fmaxf(amax, 1e-10f) / 448.0f;
  float l = (float)log2((double)v);    // correctly-rounded; exact at powers of 2
  return exp2f(ceilf(l));
}

// ---------------- kernels ----------------

// w[z][k][n] f32 -> Wt[z][n][k] bf16, 64x64 tiles, vectorized both sides.
__global__ __launch_bounds__(256) void k_transpose_cast(const float* __restrict__ W,
                                                        bf16* __restrict__ Wt) {
  __shared__ float tile[64][65];
  const size_t mat = (size_t)HID * HID;
  const float* Wz = W + mat * blockIdx.z;
  bf16* Wtz = Wt + mat * blockIdx.z;
  int bn = blockIdx.x * 64;   // n base
  int bk = blockIdx.y * 64;   // k base
  int t = threadIdx.x;
  // load: tile[k][n] via float4, rows t>>4 (+16 per pass), cols (t&15)*4
  {
    int r = t >> 4, c = (t & 15) * 4;
    #pragma unroll
    for (int i = 0; i < 4; i++) {
      float4 v = *(const float4*)(Wz + (size_t)(bk + r + 16 * i) * HID + bn + c);
      tile[r + 16 * i][c] = v.x; tile[r + 16 * i][c + 1] = v.y;
      tile[r + 16 * i][c + 2] = v.z; tile[r + 16 * i][c + 3] = v.w;
    }
  }
  __syncthreads();
  // store: thread covers n = t>>2, k in [(t&3)*16, +16) -> two bf16x8 stores
  {
    int n = t >> 2, kc = (t & 3) * 16;
    bf16x8 o0, o1;
    #pragma unroll
    for (int j = 0; j < 8; j++) o0[j] = (bf16)tile[kc + j][n];
    #pragma unroll
    for (int j = 0; j < 8; j++) o1[j] = (bf16)tile[kc + 8 + j][n];
    bf16* dst = Wtz + (size_t)(bn + n) * HID + bk + kc;
    *(bf16x8*)dst = o0;
    *(bf16x8*)(dst + 8) = o1;
  }
}

// y = rmsnorm(relu(x)) * nw -> bf16 Y;  also write relu(x) -> bf16 R (residual).
// one block per row.
__global__ __launch_bounds__(256) void k_pre(const float* __restrict__ x,
                                             const float* __restrict__ nw,
                                             bf16* __restrict__ Y,
                                             bf16* __restrict__ R) {
  size_t base = (size_t)blockIdx.x * HID + threadIdx.x * 8;
  float4 v0 = *(const float4*)(x + base);
  float4 v1 = *(const float4*)(x + base + 4);
  float z[8] = {v0.x, v0.y, v0.z, v0.w, v1.x, v1.y, v1.z, v1.w};
  float ss = 0.f;
  #pragma unroll
  for (int i = 0; i < 8; i++) { z[i] = fmaxf(z[i], 0.f); ss += z[i] * z[i]; }
  float tot = block_sum256(ss);
  float s = rsqrtf(tot * (1.0f / HID) + EPSF);
  bf16x8 rr;
  #pragma unroll
  for (int i = 0; i < 8; i++) rr[i] = (bf16)z[i];
  *(bf16x8*)(R + base) = rr;
  int j0 = threadIdx.x * 8;
  float4 w0 = *(const float4*)(nw + j0);
  float4 w1 = *(const float4*)(nw + j0 + 4);
  float wv[8] = {w0.x, w0.y, w0.z, w0.w, w1.x, w1.y, w1.z, w1.w};
  bf16x8 o;
  #pragma unroll
  for (int i = 0; i < 8; i++) o[i] = (bf16)(z[i] * s * wv[i]);
  *(bf16x8*)(Y + base) = o;
}

// resid = residIn + Cin ; y = rmsnorm(resid)*nw ; per-128-group ue8m0 quant
// -> Aout (bf16 of fp8 values), scaleOut; residOut (bf16, may alias residIn).
// one block per row; thread t covers cols [t*8, t*8+8); group g = t>>4.
__global__ __launch_bounds__(256) void k_fuse_quant(const bf16* __restrict__ residIn,
                                                    const bf16* __restrict__ Cin,
                                                    const float* __restrict__ nw,
                                                    bf16* __restrict__ residOut,
                                                    bf16* __restrict__ Aout,
                                                    float* __restrict__ scaleOut) {
  int row = blockIdx.x;
  int j0 = threadIdx.x * 8;
  size_t base = (size_t)row * HID + j0;
  bf16x8 c  = *(const bf16x8*)(Cin + base);
  bf16x8 rv = *(const bf16x8*)(residIn + base);
  float r[8]; float ss = 0.f;
  #pragma unroll
  for (int i = 0; i < 8; i++) { r[i] = (float)rv[i] + (float)c[i]; ss += r[i] * r[i]; }
  float tot = block_sum256(ss);
  float s = rsqrtf(tot * (1.0f / HID) + EPSF);

  bf16x8 ro;
  #pragma unroll
  for (int i = 0; i < 8; i++) ro[i] = (bf16)r[i];
  *(bf16x8*)(residOut + base) = ro;

  float4 w0 = *(const float4*)(nw + j0);
  float4 w1 = *(const float4*)(nw + j0 + 4);
  float wv[8] = {w0.x, w0.y, w0.z, w0.w, w1.x, w1.y, w1.z, w1.w};
  float y[8], amax = 0.f;
  #pragma unroll
  for (int i = 0; i < 8; i++) { y[i] = r[i] * s * wv[i]; amax = fmaxf(amax, fabsf(y[i])); }
  // group = 128 cols = 16 consecutive threads (within one wave)
  amax = fmaxf(amax, __shfl_xor(amax, 1, 64));
  amax = fmaxf(amax, __shfl_xor(amax, 2, 64));
  amax = fmaxf(amax, __shfl_xor(amax, 4, 64));
  amax = fmaxf(amax, __shfl_xor(amax, 8, 64));
  float scale = ue8m0_scale(amax);
  float inv = 1.0f / scale;          // exact: scale is a power of 2
  bf16x8 q;
  #pragma unroll
  for (int i = 0; i < 8; i++) {
    float t = fminf(fmaxf(y[i] * inv, -448.f), 448.f);
    q[i] = (bf16)fp8_e4m3_rne(t);    // fp8 values are exact in bf16
  }
  *(bf16x8*)(Aout + base) = q;
  if ((threadIdx.x & 15) == 0) scaleOut[(size_t)row * NGRP + (j0 >> 7)] = scale;
}

// y4 = rmsnorm(residIn + Cin) * nw -> f32 out.  one block per row.
__global__ __launch_bounds__(256) void k_final(const bf16* __restrict__ residIn,
                                               const bf16* __restrict__ Cin,
                                               const float* __restrict__ nw,
                                               float* __restrict__ out) {
  size_t base = (size_t)blockIdx.x * HID + threadIdx.x * 8;
  bf16x8 c  = *(const bf16x8*)(Cin + base);
  bf16x8 rv = *(const bf16x8*)(residIn + base);
  float r[8]; float ss = 0.f;
  #pragma unroll
  for (int i = 0; i < 8; i++) { r[i] = (float)rv[i] + (float)c[i]; ss += r[i] * r[i]; }
  float tot = block_sum256(ss);
  float s = rsqrtf(tot * (1.0f / HID) + EPSF);
  int j0 = threadIdx.x * 8;
  float4 w0 = *(const float4*)(nw + j0);
  float4 w1 = *(const float4*)(nw + j0 + 4);
  float wv[8] = {w0.x, w0.y, w0.z, w0.w, w1.x, w1.y, w1.z, w1.w};
  float4 o0, o1;
  o0.x = r[0]*s*wv[0]; o0.y = r[1]*s*wv[1]; o0.z = r[2]*s*wv[2]; o0.w = r[3]*s*wv[3];
  o1.x = r[4]*s*wv[4]; o1.y = r[5]*s*wv[5]; o1.z = r[6]*s*wv[6]; o1.w = r[7]*s*wv[7];
  *(float4*)(out + base) = o0;
  *(float4*)(out + base + 4) = o1;
}

// C[M][N] = A[M][K] * B^T[N][K], bf16 in, fp32 acc, bf16 out.
// 128x128 tile, BK=64, global_load_lds width 16, 16x16x32 MFMA, XOR-swizzled LDS.
// 1-D grid with XCD-locality mapping: XCD x serves bn in {2x, 2x+1} so each
// XCD's 4 MiB L2 holds its 1 MiB of B.
__global__ __launch_bounds__(256) void k_gemm(const bf16* __restrict__ A,
                                              const bf16* __restrict__ B,
                                              bf16* __restrict__ C,
                                              int M, int N, int K) {
  __shared__ __align__(16) bf16 As[128 * 64];
  __shared__ __align__(16) bf16 Bs[128 * 64];
  int b = blockIdx.x;
  int xcd = b & 7, j = b >> 3;
  int bn = xcd * 2 + (j & 1);
  int bm = j >> 1;
  int tid = threadIdx.x;
  int wave = tid >> 6, lane = tid & 63;
  int q = lane >> 4, rr = lane & 15;

  // staging: 4 slots per thread per matrix; slot s = wave*256 + i*64 + lane
  const bf16* Aq[4]; const bf16* Bq[4];
  #pragma unroll
  for (int i = 0; i < 4; i++) {
    int s  = wave * 256 + i * 64 + lane;
    int r  = s >> 3, c = s & 7;
    int gc = c ^ ((r >> 1) & 7);            // swizzled source chunk
    Aq[i] = A + (size_t)(bm * 128 + r) * K + gc * 8;
    Bq[i] = B + (size_t)(bn * 128 + r) * K + gc * 8;
  }
  char* AsB = (char*)As;
  char* BsB = (char*)Bs;

  f32x4 acc[4][4];
  #pragma unroll
  for (int mi = 0; mi < 4; mi++)
    #pragma unroll
    for (int ni = 0; ni < 4; ni++)
      #pragma unroll
      for (int e = 0; e < 4; e++) acc[mi][ni][e] = 0.f;

  int m_off = (wave >> 1) * 64;
  int n_off = (wave & 1) * 64;
  int swz = (rr >> 1) & 7;                  // per-lane read swizzle (row>>1)&7

  int arow[4], brow[4];
  #pragma unroll
  for (int i = 0; i < 4; i++) {
    arow[i] = (m_off + i * 16 + rr) * 64;
    brow[i] = (n_off + i * 16 + rr) * 64;
  }

  for (int k0 = 0; k0 < K; k0 += 64) {
    __syncthreads();  // all waves done reading LDS from previous iter
    #pragma unroll
    for (int i = 0; i < 4; i++)
      async_load16(Aq[i] + k0, AsB + wave * 4096 + i * 1024);
    #pragma unroll
    for (int i = 0; i < 4; i++)
      async_load16(Bq[i] + k0, BsB + wave * 4096 + i * 1024);
    __syncthreads();  // vmcnt(0) drain: staged tile visible

    #pragma unroll
    for (int ms = 0; ms < 2; ms++) {
      int p = ((ms * 4 + q) ^ swz) * 8;     // swizzled chunk -> element offset
      bf16x8 af[4], bfr[4];
      #pragma unroll
      for (int mi = 0; mi < 4; mi++)
        af[mi] = *(const bf16x8*)(As + arow[mi] + p);
      #pragma unroll
      for (int ni = 0; ni < 4; ni++)
        bfr[ni] = *(const bf16x8*)(Bs + brow[ni] + p);
      #pragma unroll
      for (int mi = 0; mi < 4; mi++)
        #pragma unroll
        for (int ni = 0; ni < 4; ni++)
          acc[mi][ni] = __builtin_amdgcn_mfma_f32_16x16x32_bf16(af[mi], bfr[ni], acc[mi][ni], 0, 0, 0);
    }
  }

  // epilogue: C/D layout col=lane&15, row=(lane>>4)*4+reg
  #pragma unroll
  for (int mi = 0; mi < 4; mi++)
    #pragma unroll
    for (int ni = 0; ni < 4; ni++)
      #pragma unroll
      for (int t = 0; t < 4; t++) {
        int rowi = bm * 128 + m_off + mi * 16 + q * 4 + t;
        int coli = bn * 128 + n_off + ni * 16 + rr;
        C[(size_t)rowi * N + coli] = (bf16)acc[mi][ni][t];
      }
}

// ---------------- launch ----------------

extern "C" void kernel_launch(void* const* d_in, const int* in_sizes, int n_in,
                              void* d_out, int out_size, void* d_ws, size_t ws_size,
                              hipStream_t stream) {
  const float* x      = (const float*)d_in[0];
  const float* norm_w = (const float*)d_in[1];
  const float* w      = (const float*)d_in[2];

  float* out   = (float*)d_out;
  float* y4o   = out;
  float* s2o   = out + (size_t)NTOK * HID;           // y2_s [16384,16]
  float* s3o   = s2o + (size_t)NTOK * NGRP;          // y3_s [16384,16]

  char* ws = (char*)d_ws;
  const size_t WT_B = (size_t)3 * HID * HID * 2;     // 25,165,824
  const size_t AB_B = (size_t)NTOK * HID * 2;        // 67,108,864
  bf16* Wt   = (bf16*)ws;
  bf16* Abuf = (bf16*)(ws + WT_B);
  bf16* Cbuf = (bf16*)(ws + WT_B + AB_B);
  bf16* Rbuf = (bf16*)(ws + WT_B + 2 * AB_B);
  const size_t MATE = (size_t)HID * HID;

  dim3 gT(HID / 64, HID / 64, 3);
  int  gG = (HID / 128) * (NTOK / 128);    // 1-D swizzled grid

  k_transpose_cast<<<gT, 256, 0, stream>>>(w, Wt);
  k_pre<<<NTOK, 256, 0, stream>>>(x, norm_w, Abuf, Rbuf);
  k_gemm<<<gG, 256, 0, stream>>>(Abuf, Wt, Cbuf, NTOK, HID, HID);
  k_fuse_quant<<<NTOK, 256, 0, stream>>>(Rbuf, Cbuf, norm_w + HID, Rbuf, Abuf, s2o);
  k_gemm<<<gG, 256, 0, stream>>>(Abuf, Wt + MATE, Cbuf, NTOK, HID, HID);
  k_fuse_quant<<<NTOK, 256, 0, stream>>>(Rbuf, Cbuf, norm_w + 2 * HID, Rbuf, Abuf, s3o);
  k_gemm<<<gG, 256, 0, stream>>>(Abuf, Wt + 2 * MATE, Cbuf, NTOK, HID, HID);
  k_final<<<NTOK, 256, 0, stream>>>(Rbuf, Cbuf, norm_w + 3 * HID, y4o);
}